// Round 15
// baseline (1065.481 us; speedup 1.0000x reference)
//
#include <hip/hip_runtime.h>
#include <hip/hip_bf16.h>
#include <math.h>

#define B_ 4
#define T_ 1024
#define O_ 128
#define D_ 512
#define H_ 8
#define L_ 6
#define TK_ 2176
#define MM_ 100000
#define EH_ 4
#define EHD_ 128
#define HD_ 64

typedef float f32x4 __attribute__((ext_vector_type(4)));
typedef short bf16x8 __attribute__((ext_vector_type(8)));
typedef unsigned short u16;

// PRIMES per reference: base=131, x=base+h*1009; row[i]=x; x=x*31+1 (uint32 wrap)
__device__ __constant__ unsigned int PRIMES_[4][4] = {
  {131u,  4062u,  125923u, 3903614u},
  {1140u, 35341u, 1095572u, 33962733u},
  {2149u, 66620u, 2065221u, 64021852u},
  {3158u, 97899u, 3034870u, 94080971u},
};

__device__ __forceinline__ float wave_sum_f(float v) {
  #pragma unroll
  for (int off = 32; off; off >>= 1) v += __shfl_xor(v, off);
  return v;
}

__device__ __forceinline__ short f2bf(float f) {
  unsigned int u = __float_as_uint(f);
  unsigned int r = (u + 0x7fffu + ((u >> 16) & 1u)) >> 16;
  return (short)r;
}

__device__ __forceinline__ void gload16(const void* g, void* l) {
  __builtin_amdgcn_global_load_lds((const __attribute__((address_space(1))) void*)g,
                                   (__attribute__((address_space(3))) void*)l, 16, 0, 0);
}

// repack within a 16-lane group: input p = bf16(col lr) | bf16(col lr+16)<<16
// output = bf16(col 2*lr) | bf16(col 2*lr+1)<<16  -> 16-lane group covers 64
// contiguous bytes of one row (64 B sector-aligned store).
__device__ __forceinline__ unsigned int repack32(unsigned int p, int lane) {
  int lr = lane & 15;
  int gb = lane & 48;
  unsigned int s0 = __shfl(p, gb + ((2 * lr) & 15), 64);
  unsigned int s1 = __shfl(p, gb + ((2 * lr + 1) & 15), 64);
  return (lr < 8) ? ((s0 & 0xffffu) | (s1 << 16))
                  : ((s0 >> 16) | (s1 & 0xffff0000u));
}

// ---------------- rope tables: cos/sin [TK][32] ----------------
__global__ __launch_bounds__(64) void rope_table_k(float* __restrict__ rc,
                                                   float* __restrict__ rs) {
  int i = blockIdx.x * 64 + threadIdx.x;
  int t = i >> 5, j = i & 31;
  float freq = __powf(10000.0f, -(float)j / 32.0f);
  float ang = (float)t * freq;
  rc[i] = cosf(ang);
  rs[i] = sinf(ang);
}

// ---------------- ssum @ ssum_W -> ssp[B][D] ----------------
__global__ __launch_bounds__(256) void ssum_proj_k(const float* __restrict__ ssum,
                                                   const float* __restrict__ sW,
                                                   float* __restrict__ ssp) {
  int col = blockIdx.x * 256 + threadIdx.x;
  int b = blockIdx.y;
  float acc = 0.f;
  for (int d = 0; d < D_; ++d) acc += ssum[b * D_ + d] * sW[(size_t)d * D_ + col];
  ssp[b * D_ + col] = acc;
}

// ---------------- f32 tiled GEMM (preamble mem projection only) ----------------
__global__ __launch_bounds__(256) void sgemm_k(const float* __restrict__ A,
                                               const float* __restrict__ W,
                                               const float* __restrict__ bias,
                                               float* __restrict__ C,
                                               int M, int N, int K) {
  __shared__ float As[16][68];
  __shared__ float Bs[16][68];
  int tid = threadIdx.x;
  int row0 = blockIdx.y * 64;
  int col0 = blockIdx.x * 64;
  int tx = tid & 15, ty = tid >> 4;
  int am = tid >> 2, ak = (tid & 3) * 4;
  int bk = tid >> 4, bc = (tid & 15) * 4;
  float acc[4][4] = {};
  for (int k0 = 0; k0 < K; k0 += 16) {
    float4 av = *reinterpret_cast<const float4*>(&A[(size_t)(row0 + am) * K + k0 + ak]);
    As[ak + 0][am] = av.x; As[ak + 1][am] = av.y; As[ak + 2][am] = av.z; As[ak + 3][am] = av.w;
    float4 bv = *reinterpret_cast<const float4*>(&W[(size_t)(k0 + bk) * N + col0 + bc]);
    *reinterpret_cast<float4*>(&Bs[bk][bc]) = bv;
    __syncthreads();
    #pragma unroll
    for (int kk = 0; kk < 16; ++kk) {
      float4 a4 = *reinterpret_cast<const float4*>(&As[kk][ty * 4]);
      float4 b4 = *reinterpret_cast<const float4*>(&Bs[kk][tx * 4]);
      float a[4] = {a4.x, a4.y, a4.z, a4.w};
      float b[4] = {b4.x, b4.y, b4.z, b4.w};
      #pragma unroll
      for (int i = 0; i < 4; ++i)
        #pragma unroll
        for (int j = 0; j < 4; ++j) acc[i][j] += a[i] * b[j];
    }
    __syncthreads();
  }
  int cbase = col0 + tx * 4;
  float4 b4 = *reinterpret_cast<const float4*>(&bias[cbase]);
  float bb[4] = {b4.x, b4.y, b4.z, b4.w};
  #pragma unroll
  for (int i = 0; i < 4; ++i) {
    int row = row0 + ty * 4 + i;
    *reinterpret_cast<float4*>(&C[(size_t)row * N + cbase]) =
        make_float4(acc[i][0] + bb[0], acc[i][1] + bb[1], acc[i][2] + bb[2], acc[i][3] + bb[3]);
  }
}

// ---------------- batched weight convert+transpose: f32 [K][N] -> bf16 [N][K] ----------------
__device__ __forceinline__ void wconv_tile(const float* __restrict__ W, u16* __restrict__ wT,
                                           int K, int N) {
  __shared__ float s[64][65];
  int n0 = blockIdx.x * 64, k0 = blockIdx.y * 64;
  int tid = threadIdx.x;
  int kr = tid >> 4, nc = (tid & 15) * 4;
  #pragma unroll
  for (int kk = 0; kk < 4; ++kk) {
    float4 f = *reinterpret_cast<const float4*>(&W[(size_t)(k0 + kr + kk * 16) * N + n0 + nc]);
    s[kr + kk * 16][nc + 0] = f.x; s[kr + kk * 16][nc + 1] = f.y;
    s[kr + kk * 16][nc + 2] = f.z; s[kr + kk * 16][nc + 3] = f.w;
  }
  __syncthreads();
  int nr = tid >> 4, kc = (tid & 15) * 4;
  #pragma unroll
  for (int nn = 0; nn < 4; ++nn) {
    int n = nr + nn * 16;
    ushort4 o;
    o.x = (u16)f2bf(s[kc + 0][n]); o.y = (u16)f2bf(s[kc + 1][n]);
    o.z = (u16)f2bf(s[kc + 2][n]); o.w = (u16)f2bf(s[kc + 3][n]);
    *reinterpret_cast<ushort4*>(&wT[(size_t)(n0 + n) * K + k0 + kc]) = o;
  }
}

__global__ __launch_bounds__(256) void wconv_qkvo_k(const float* __restrict__ qW,
                                                    const float* __restrict__ kW,
                                                    const float* __restrict__ vW,
                                                    const float* __restrict__ oW,
                                                    u16* __restrict__ dst) {
  int z = blockIdx.z;
  int l = z >> 2, which = z & 3;
  const float* src = which == 0 ? qW : which == 1 ? kW : which == 2 ? vW : oW;
  wconv_tile(src + (size_t)l * D_ * D_, dst + (size_t)z * D_ * D_, D_, D_);
}

__global__ __launch_bounds__(256) void wconv_win_k(const float* __restrict__ w_in,
                                                   u16* __restrict__ dst) {
  int l = blockIdx.z;
  wconv_tile(w_in + (size_t)l * 512 * 4096, dst + (size_t)l * 4096 * 512, 512, 4096);
}

__global__ __launch_bounds__(256) void wconv_wout_k(const float* __restrict__ w_out,
                                                    u16* __restrict__ dst) {
  int l = blockIdx.z;
  wconv_tile(w_out + (size_t)l * 2048 * 512, dst + (size_t)l * 512 * 2048, 2048, 512);
}

// ---------------- small MFMA GEMM: 64x64 tile, 4 waves (wave 32x32) ----------------
template<int EPI>
__global__ __launch_bounds__(256) void gemm_sm_k(const u16* __restrict__ A,
                                                 const u16* __restrict__ Bt,
                                                 const float* __restrict__ bias,
                                                 void* __restrict__ Cout,
                                                 int M, int N, int K, int posmod,
                                                 const float* __restrict__ rc,
                                                 const float* __restrict__ rs) {
  __shared__ __align__(16) u16 As[2][64 * 32];
  __shared__ __align__(16) u16 Bs[2][64 * 32];
  int tid = threadIdx.x;
  int w = tid >> 6, lane = tid & 63;
  int lr = lane & 15, lg = lane >> 4;
  int row0 = blockIdx.y * 64, col0 = blockIdx.x * 64;
  int wr = w >> 1, wc = w & 1;
  f32x4 acc[2][2] = {};

  int srow = tid >> 2;
  int skel = (tid & 3) * 8;

  auto stage = [&](int buf, int k0) {
    gload16(A + (size_t)(row0 + srow) * K + k0 + skel, &As[buf][srow * 32 + skel]);
    gload16(Bt + (size_t)(col0 + srow) * K + k0 + skel, &Bs[buf][srow * 32 + skel]);
  };

  stage(0, 0);
  __syncthreads();
  int nk = K >> 5;
  int buf = 0;
  for (int t = 0; t < nk; ++t) {
    if (t + 1 < nk) stage(buf ^ 1, (t + 1) * 32);
    bf16x8 af[2], bf[2];
    #pragma unroll
    for (int i = 0; i < 2; ++i)
      af[i] = *reinterpret_cast<const bf16x8*>(&As[buf][(wr * 32 + i * 16 + lr) * 32 + lg * 8]);
    #pragma unroll
    for (int j = 0; j < 2; ++j)
      bf[j] = *reinterpret_cast<const bf16x8*>(&Bs[buf][(wc * 32 + j * 16 + lr) * 32 + lg * 8]);
    #pragma unroll
    for (int i = 0; i < 2; ++i)
      #pragma unroll
      for (int j = 0; j < 2; ++j)
        acc[i][j] = __builtin_amdgcn_mfma_f32_16x16x32_bf16(af[i], bf[j], acc[i][j], 0, 0, 0);
    __syncthreads();
    buf ^= 1;
  }

  #pragma unroll
  for (int j = 0; j < 2; ++j) {
    int col = col0 + wc * 32 + j * 16 + lr;
    float bs = bias ? bias[col] : 0.f;
    #pragma unroll
    for (int i = 0; i < 2; ++i) {
      #pragma unroll
      for (int r = 0; r < 4; ++r) {
        int row = row0 + wr * 32 + i * 16 + lg * 4 + r;
        float v = acc[i][j][r] + bs;
        if (EPI == 1) {
          int pos = row % posmod;
          int d = col & 63;
          float c = rc[(size_t)pos * 32 + (d >> 1)];
          float s = rs[(size_t)pos * 32 + (d >> 1)];
          float partner = __shfl_xor(v, 1);
          v = (d & 1) ? (partner * s + v * c) : (v * c - partner * s);
        }
        if (EPI == 2) {
          float* Cf = (float*)Cout;
          Cf[(size_t)row * N + col] += v;
        } else {
          u16* Cb = (u16*)Cout;
          Cb[(size_t)row * N + col] = (u16)f2bf(v);
        }
      }
    }
  }
}

// ---------------- fused K+V projection, XCD-pinned grid, repacked 64B stores ----------------
// 1D grid: bid = c + 8*(x + 8*(yh + 9*z)); y = yh*8 + c. bid%8 = y%8 pins all
// col-blocks + all layers of row-stripe y to one XCD -> A stays L2-resident.
// Epilogue repacks (j0,j1) pairs across the 16-lane group via 2 shfls so each
// group stores 64 contiguous 64B-aligned bytes per row (kills 2x write-sector
// amplification of scattered 32B u16 chunks).
__global__ __launch_bounds__(256) void kv_gemm_k(const u16* __restrict__ A,
                                                 const u16* __restrict__ wqkvoT,
                                                 const float* __restrict__ kbias_all,
                                                 const float* __restrict__ vbias_all,
                                                 u16* __restrict__ kb_base,
                                                 u16* __restrict__ vb_base,
                                                 const float* __restrict__ rc,
                                                 const float* __restrict__ rs,
                                                 int l0, size_t ostride) {
  __shared__ __align__(16) u16 As[2][128 * 32];
  __shared__ __align__(16) u16 Bk[2][64 * 32];
  __shared__ __align__(16) u16 Bv[2][64 * 32];
  const int K = 512, N = 512;
  int bid = blockIdx.x;
  int c_ = bid & 7;
  int x_ = (bid >> 3) & 7;
  int rest = bid >> 6;
  int yh = rest % 9;
  int z = rest / 9;
  int y_ = yh * 8 + c_;
  if (y_ >= 68) return;
  int l = l0 + z;
  const u16* wkT = wqkvoT + ((size_t)l * 4 + 1) * (D_ * D_);
  const u16* wvT = wqkvoT + ((size_t)l * 4 + 2) * (D_ * D_);
  const float* kbias = kbias_all + l * D_;
  const float* vbias = vbias_all + l * D_;
  u16* kb = kb_base + (size_t)z * ostride;
  u16* vb = vb_base + (size_t)z * ostride;
  int tid = threadIdx.x;
  int w = tid >> 6, lane = tid & 63;
  int lr = lane & 15, lg = lane >> 4;
  int row0 = y_ * 128, col0 = x_ * 64;
  int wr = w >> 1, wc = w & 1;
  f32x4 ak_[4][2] = {};
  f32x4 av_[4][2] = {};

  int srow = lane >> 2;
  int skel = (lane & 3) * 8;

  auto stage = [&](int buf, int k0) {
    #pragma unroll
    for (int ci = 0; ci < 2; ++ci) {
      int c = w * 2 + ci;
      gload16(A + (size_t)(row0 + c * 16 + srow) * K + k0 + skel, &As[buf][c * 512]);
    }
    gload16(wkT + (size_t)(col0 + w * 16 + srow) * K + k0 + skel, &Bk[buf][w * 512]);
    gload16(wvT + (size_t)(col0 + w * 16 + srow) * K + k0 + skel, &Bv[buf][w * 512]);
  };

  stage(0, 0);
  __syncthreads();
  int buf = 0;
  for (int t = 0; t < 16; ++t) {
    if (t + 1 < 16) stage(buf ^ 1, (t + 1) * 32);
    bf16x8 af[4], bk[2], bv[2];
    #pragma unroll
    for (int i = 0; i < 4; ++i)
      af[i] = *reinterpret_cast<const bf16x8*>(&As[buf][(wr * 64 + i * 16 + lr) * 32 + lg * 8]);
    #pragma unroll
    for (int j = 0; j < 2; ++j) {
      bk[j] = *reinterpret_cast<const bf16x8*>(&Bk[buf][(wc * 32 + j * 16 + lr) * 32 + lg * 8]);
      bv[j] = *reinterpret_cast<const bf16x8*>(&Bv[buf][(wc * 32 + j * 16 + lr) * 32 + lg * 8]);
    }
    #pragma unroll
    for (int i = 0; i < 4; ++i)
      #pragma unroll
      for (int j = 0; j < 2; ++j) {
        ak_[i][j] = __builtin_amdgcn_mfma_f32_16x16x32_bf16(af[i], bk[j], ak_[i][j], 0, 0, 0);
        av_[i][j] = __builtin_amdgcn_mfma_f32_16x16x32_bf16(af[i], bv[j], av_[i][j], 0, 0, 0);
      }
    __syncthreads();
    buf ^= 1;
  }

  // epilogue: per (i,r) compute both j values, rope+bias, pack -> repack -> u32 store
  int c0 = col0 + wc * 32 + lr;
  int c1 = c0 + 16;
  float kbs0 = kbias[c0], kbs1 = kbias[c1];
  float vbs0 = vbias[c0], vbs1 = vbias[c1];
  int d0 = c0 & 63, d1 = c1 & 63;
  size_t colbase = col0 + wc * 32 + 2 * lr;
  #pragma unroll
  for (int i = 0; i < 4; ++i) {
    #pragma unroll
    for (int r = 0; r < 4; ++r) {
      int row = row0 + wr * 64 + i * 16 + lg * 4 + r;
      int pos = row % TK_;
      float k0v = ak_[i][0][r] + kbs0;
      {
        float c = rc[(size_t)pos * 32 + (d0 >> 1)];
        float s = rs[(size_t)pos * 32 + (d0 >> 1)];
        float partner = __shfl_xor(k0v, 1);
        k0v = (d0 & 1) ? (partner * s + k0v * c) : (k0v * c - partner * s);
      }
      float k1v = ak_[i][1][r] + kbs1;
      {
        float c = rc[(size_t)pos * 32 + (d1 >> 1)];
        float s = rs[(size_t)pos * 32 + (d1 >> 1)];
        float partner = __shfl_xor(k1v, 1);
        k1v = (d1 & 1) ? (partner * s + k1v * c) : (k1v * c - partner * s);
      }
      unsigned int pk = (unsigned int)(u16)f2bf(k0v) | ((unsigned int)(u16)f2bf(k1v) << 16);
      *reinterpret_cast<unsigned int*>(&kb[(size_t)row * N + colbase]) = repack32(pk, lane);
      float v0v = av_[i][0][r] + vbs0;
      float v1v = av_[i][1][r] + vbs1;
      unsigned int pv = (unsigned int)(u16)f2bf(v0v) | ((unsigned int)(u16)f2bf(v1v) << 16);
      *reinterpret_cast<unsigned int*>(&vb[(size_t)row * N + colbase]) = repack32(pv, lane);
    }
  }
}

// ---------------- fused MLP-in MFMA (64-col dual tile, repacked 64B stores) ----------------
__global__ __launch_bounds__(256) void mlp_in_mfma_k(const u16* __restrict__ A,
                                                     const u16* __restrict__ wiT,
                                                     u16* __restrict__ Hout) {
  __shared__ __align__(16) u16 As[2][128 * 32];
  __shared__ __align__(16) u16 Bg[2][64 * 32];
  __shared__ __align__(16) u16 Bv[2][64 * 32];
  int tid = threadIdx.x;
  int w = tid >> 6, lane = tid & 63;
  int lr = lane & 15, lg = lane >> 4;
  int hc0 = blockIdx.x * 64, row0 = blockIdx.y * 128;
  int wr = w >> 1, wc = w & 1;
  f32x4 ag[4][2] = {};
  f32x4 av[4][2] = {};
  const int K = 512;

  int srow = lane >> 2;
  int skel = (lane & 3) * 8;

  auto stage = [&](int buf, int k0) {
    #pragma unroll
    for (int ci = 0; ci < 2; ++ci) {
      int c = w * 2 + ci;
      gload16(A + (size_t)(row0 + c * 16 + srow) * K + k0 + skel, &As[buf][c * 512]);
    }
    gload16(wiT + (size_t)(hc0 + w * 16 + srow) * K + k0 + skel, &Bg[buf][w * 512]);
    gload16(wiT + (size_t)(2048 + hc0 + w * 16 + srow) * K + k0 + skel, &Bv[buf][w * 512]);
  };

  stage(0, 0);
  __syncthreads();
  int buf = 0;
  for (int t = 0; t < 16; ++t) {
    if (t + 1 < 16) stage(buf ^ 1, (t + 1) * 32);
    bf16x8 af[4], bg[2], bv[2];
    #pragma unroll
    for (int i = 0; i < 4; ++i)
      af[i] = *reinterpret_cast<const bf16x8*>(&As[buf][(wr * 64 + i * 16 + lr) * 32 + lg * 8]);
    #pragma unroll
    for (int j = 0; j < 2; ++j) {
      bg[j] = *reinterpret_cast<const bf16x8*>(&Bg[buf][(wc * 32 + j * 16 + lr) * 32 + lg * 8]);
      bv[j] = *reinterpret_cast<const bf16x8*>(&Bv[buf][(wc * 32 + j * 16 + lr) * 32 + lg * 8]);
    }
    #pragma unroll
    for (int i = 0; i < 4; ++i)
      #pragma unroll
      for (int j = 0; j < 2; ++j) {
        ag[i][j] = __builtin_amdgcn_mfma_f32_16x16x32_bf16(af[i], bg[j], ag[i][j], 0, 0, 0);
        av[i][j] = __builtin_amdgcn_mfma_f32_16x16x32_bf16(af[i], bv[j], av[i][j], 0, 0, 0);
      }
    __syncthreads();
    buf ^= 1;
  }

  size_t colbase = hc0 + wc * 32 + 2 * lr;
  #pragma unroll
  for (int i = 0; i < 4; ++i) {
    #pragma unroll
    for (int r = 0; r < 4; ++r) {
      int row = row0 + wr * 64 + i * 16 + lg * 4 + r;
      float g0 = ag[i][0][r];
      float h0 = g0 / (1.f + __expf(-g0)) * av[i][0][r];
      float g1 = ag[i][1][r];
      float h1 = g1 / (1.f + __expf(-g1)) * av[i][1][r];
      unsigned int ph = (unsigned int)(u16)f2bf(h0) | ((unsigned int)(u16)f2bf(h1) << 16);
      *reinterpret_cast<unsigned int*>(&Hout[(size_t)row * 2048 + colbase]) = repack32(ph, lane);
    }
  }
}

// ---------------- rmsnorm rows ----------------
template<int OUTBF>
__global__ __launch_bounds__(128) void rmsnorm_k(const float* __restrict__ in,
                                                 const float* __restrict__ scale,
                                                 void* __restrict__ out) {
  int row = blockIdx.x;
  int tid = threadIdx.x;
  float4 v = *reinterpret_cast<const float4*>(&in[(size_t)row * D_ + tid * 4]);
  float ss = v.x * v.x + v.y * v.y + v.z * v.z + v.w * v.w;
  ss = wave_sum_f(ss);
  __shared__ float red[2];
  if ((tid & 63) == 0) red[tid >> 6] = ss;
  __syncthreads();
  ss = red[0] + red[1];
  float inv = 1.0f / sqrtf(ss / (float)D_ + 1e-6f);
  float4 sc = *reinterpret_cast<const float4*>(&scale[tid * 4]);
  float o0 = v.x * inv * sc.x, o1 = v.y * inv * sc.y, o2 = v.z * inv * sc.z, o3 = v.w * inv * sc.w;
  if (OUTBF) {
    ushort4 o;
    o.x = (u16)f2bf(o0); o.y = (u16)f2bf(o1); o.z = (u16)f2bf(o2); o.w = (u16)f2bf(o3);
    *reinterpret_cast<ushort4*>((u16*)out + (size_t)row * D_ + tid * 4) = o;
  } else {
    *reinterpret_cast<float4*>((float*)out + (size_t)row * D_ + tid * 4) =
        make_float4(o0, o1, o2, o3);
  }
}

// ---------------- mem rows ----------------
__global__ __launch_bounds__(128) void memnorm_k(const float* __restrict__ tmp,
                                                 const float* __restrict__ scale,
                                                 u16* __restrict__ kv) {
  int o = blockIdx.x, b = blockIdx.y;
  int tid = threadIdx.x;
  float4 v = *reinterpret_cast<const float4*>(&tmp[(size_t)(b * O_ + o) * D_ + tid * 4]);
  float ss = v.x * v.x + v.y * v.y + v.z * v.z + v.w * v.w;
  ss = wave_sum_f(ss);
  __shared__ float red[2];
  if ((tid & 63) == 0) red[tid >> 6] = ss;
  __syncthreads();
  ss = red[0] + red[1];
  float inv = 1.0f / sqrtf(ss / (float)D_ + 1e-6f);
  float4 sc = *reinterpret_cast<const float4*>(&scale[tid * 4]);
  ushort4 oo;
  oo.x = (u16)f2bf(v.x * inv * sc.x); oo.y = (u16)f2bf(v.y * inv * sc.y);
  oo.z = (u16)f2bf(v.z * inv * sc.z); oo.w = (u16)f2bf(v.w * inv * sc.w);
  *reinterpret_cast<ushort4*>(&kv[(size_t)(b * TK_ + o) * D_ + tid * 4]) = oo;
}

// ---------------- engram rows ----------------
__global__ __launch_bounds__(128) void engram_k(const int* __restrict__ tokens,
                                                const int* __restrict__ mem_ids,
                                                const float* __restrict__ etab,
                                                const float* __restrict__ egate,
                                                const float* __restrict__ escale,
                                                u16* __restrict__ kv) {
  int t = blockIdx.x, b = blockIdx.y;
  int tid = threadIdx.x;
  unsigned int toks[4];
  #pragma unroll
  for (int i = 0; i < 4; ++i) {
    int idx = t - i;
    toks[i] = (idx >= 0) ? (unsigned int)tokens[b * T_ + idx]
                         : (unsigned int)mem_ids[b * O_ + O_ + idx];
  }
  int c = tid * 4;
  int h = c >> 7;
  int e = c & 127;
  unsigned int hs = 0;
  #pragma unroll
  for (int i = 0; i < 4; ++i) hs += toks[i] * PRIMES_[h][i];
  int idxh = (int)(hs % (unsigned int)MM_);
  float4 r = *reinterpret_cast<const float4*>(&etab[((size_t)idxh * EH_ + h) * EHD_ + e]);
  float4 g = *reinterpret_cast<const float4*>(&egate[h * EHD_ + e]);
  float4 val;
  val.x = r.x / (1.f + __expf(-g.x));
  val.y = r.y / (1.f + __expf(-g.y));
  val.z = r.z / (1.f + __expf(-g.z));
  val.w = r.w / (1.f + __expf(-g.w));
  float ss = val.x * val.x + val.y * val.y + val.z * val.z + val.w * val.w;
  ss = wave_sum_f(ss);
  __shared__ float red[2];
  if ((tid & 63) == 0) red[tid >> 6] = ss;
  __syncthreads();
  ss = red[0] + red[1];
  float inv = 1.0f / sqrtf(ss / (float)D_ + 1e-6f);
  float4 sc = *reinterpret_cast<const float4*>(&escale[c]);
  ushort4 oo;
  oo.x = (u16)f2bf(val.x * inv * sc.x); oo.y = (u16)f2bf(val.y * inv * sc.y);
  oo.z = (u16)f2bf(val.z * inv * sc.z); oo.w = (u16)f2bf(val.w * inv * sc.w);
  *reinterpret_cast<ushort4*>(&kv[(size_t)(b * TK_ + O_ + t) * D_ + c]) = oo;
}

// ---------------- embed + ssum inject ----------------
__global__ __launch_bounds__(128) void embed_k(const int* __restrict__ tokens,
                                               const float* __restrict__ etab,
                                               const float* __restrict__ ssp,
                                               const float* __restrict__ alpha_g,
                                               float* __restrict__ cx,
                                               u16* __restrict__ kv) {
  int t = blockIdx.x, b = blockIdx.y;
  int tid = threadIdx.x;
  int c = tid * 4;
  int tok = tokens[b * T_ + t];
  float4 e = *reinterpret_cast<const float4*>(&etab[(size_t)tok * D_ + c]);
  float4 sp = *reinterpret_cast<const float4*>(&ssp[b * D_ + c]);
  float4 ag = *reinterpret_cast<const float4*>(&alpha_g[c]);
  float4 x;
  x.x = e.x + sp.x / (1.f + __expf(-ag.x));
  x.y = e.y + sp.y / (1.f + __expf(-ag.y));
  x.z = e.z + sp.z / (1.f + __expf(-ag.z));
  x.w = e.w + sp.w / (1.f + __expf(-ag.w));
  *reinterpret_cast<float4*>(&cx[(size_t)(b * T_ + t) * D_ + c]) = x;
  ushort4 oo;
  oo.x = (u16)f2bf(x.x); oo.y = (u16)f2bf(x.y);
  oo.z = (u16)f2bf(x.z); oo.w = (u16)f2bf(x.w);
  *reinterpret_cast<ushort4*>(&kv[(size_t)(b * TK_ + O_ + T_ + t) * D_ + c]) = oo;
}

// ---------------- MFMA flash attention v6: KVBLK=128, paired q-tiles ----------------
#define KIDX8(r, c) (((r) << 6) + ((c) ^ (((r) & 7) << 3)))
#define VIDX(d, c)  (((d) << 7) + ((c) ^ (((d) & 15) << 2)))
#define PIDX2(q, o) (((q) << 6) + ((o) ^ (((q) & 15) << 2)))

__global__ __launch_bounds__(512) void attn_mfma_k(const u16* __restrict__ qb,
                                                   const u16* __restrict__ kb,
                                                   const u16* __restrict__ vb,
                                                   const int* __restrict__ tokens,
                                                   u16* __restrict__ ob) {
  __shared__ __align__(16) short ks[2][128 * 64];
  __shared__ __align__(16) short vst[2][64 * 128];        // transposed: [d][k]
  __shared__ __align__(16) unsigned int pbuf[8][16 * 64]; // per-wave P^T packed pairs
  __shared__ unsigned char vtok[T_];

  int fid = blockIdx.x;       // 256 blocks
  int h = fid & 7;
  int s = fid >> 3;           // 0..31
  int pair = s & 7;           // bxA = pair, bxB = 15 - pair
  int b = s >> 3;             // 0..3
  int bxA = pair, bxB = 15 - pair;

  int tid = threadIdx.x;
  int w = tid >> 6, lane = tid & 63;
  int lr = lane & 15;
  int lg = lane >> 4;
  int myBx = (w < 4) ? bxA : bxB;
  int qw0 = myBx * 64 + (w & 3) * 16;
  int tq = qw0 + lr;  // this lane's query row

  for (int i = tid; i < T_; i += 512) vtok[i] = (tokens[b * T_ + i] != 0);

  bf16x8 aq[2];  // Q for this lane's q row: B-operand (col=lr, d=lg*8..)
  {
    const u16* qp = &qb[((size_t)(b * T_) + tq) * D_ + h * 64];
    aq[0] = *reinterpret_cast<const bf16x8*>(qp + lg * 8);
    aq[1] = *reinterpret_cast<const bf16x8*>(qp + 32 + lg * 8);
  }

  float m_ = -1e30f, lsum = 0.f;
  f32x4 od[4];
  #pragma unroll
  for (int dt = 0; dt < 4; ++dt) od[dt] = (f32x4){0.f, 0.f, 0.f, 0.f};

  int sr = tid >> 2;
  int sc = (tid & 3) * 16;
  int k4 = (tid >> 4) * 4;
  int vc = (tid & 15) * 4;

  int te = (bxB >> 1) + 1;
  int myTe = myBx >> 1;
  int nt = 1 + 2 * te;
  auto tile_pos = [&](int i, int& pos0, int& base, bool& masked, bool& part) {
    if (i < 1) { pos0 = 0; base = 0; masked = false; part = true; }
    else if (i < 1 + te) {
      int t = i - 1;
      pos0 = O_ + t * 128; base = O_; masked = true; part = (t <= myTe);
    } else {
      int t = i - 1 - te;
      pos0 = O_ + T_ + t * 128; base = O_ + T_; masked = true; part = (t <= myTe);
    }
  };

  bf16x8 pk0, pk1;
  short4 pv0, pv1, pv2, pv3;

  auto load_regs = [&](int pos0) {
    const u16* kg = &kb[((size_t)(b * TK_) + pos0 + sr) * D_ + h * 64 + sc];
    pk0 = *reinterpret_cast<const bf16x8*>(kg);
    pk1 = *reinterpret_cast<const bf16x8*>(kg + 8);
    const u16* vg = &vb[((size_t)(b * TK_) + pos0 + k4) * D_ + h * 64 + vc];
    pv0 = *reinterpret_cast<const short4*>(vg);
    pv1 = *reinterpret_cast<const short4*>(vg + D_);
    pv2 = *reinterpret_cast<const short4*>(vg + 2 * D_);
    pv3 = *reinterpret_cast<const short4*>(vg + 3 * D_);
  };

  auto write_lds = [&](int buf) {
    *reinterpret_cast<bf16x8*>(&ks[buf][KIDX8(sr, sc)]) = pk0;
    *reinterpret_cast<bf16x8*>(&ks[buf][KIDX8(sr, sc + 8)]) = pk1;
    short4 t0 = make_short4(pv0.x, pv1.x, pv2.x, pv3.x);
    short4 t1 = make_short4(pv0.y, pv1.y, pv2.y, pv3.y);
    short4 t2 = make_short4(pv0.z, pv1.z, pv2.z, pv3.z);
    short4 t3 = make_short4(pv0.w, pv1.w, pv2.w, pv3.w);
    *reinterpret_cast<short4*>(&vst[buf][VIDX(vc + 0, k4)]) = t0;
    *reinterpret_cast<short4*>(&vst[buf][VIDX(vc + 1, k4)]) = t1;
    *reinterpret_cast<short4*>(&vst[buf][VIDX(vc + 2, k4)]) = t2;
    *reinterpret_cast<short4*>(&vst[buf][VIDX(vc + 3, k4)]) = t3;
  };

  unsigned int* pw = (unsigned int*)pbuf[w];

  auto compute = [&](int buf, int pos0, int base, bool masked) {
    float sv[8][4];
    __builtin_amdgcn_s_setprio(1);
    #pragma unroll
    for (int kt = 0; kt < 8; ++kt) {
      bf16x8 ka0 = *reinterpret_cast<const bf16x8*>(&ks[buf][KIDX8(kt * 16 + lr, lg * 8)]);
      bf16x8 ka1 = *reinterpret_cast<const bf16x8*>(&ks[buf][KIDX8(kt * 16 + lr, 32 + lg * 8)]);
      f32x4 sf = (f32x4){0.f, 0.f, 0.f, 0.f};
      sf = __builtin_amdgcn_mfma_f32_16x16x32_bf16(ka0, aq[0], sf, 0, 0, 0);
      sf = __builtin_amdgcn_mfma_f32_16x16x32_bf16(ka1, aq[1], sf, 0, 0, 0);
      #pragma unroll
      for (int r = 0; r < 4; ++r) sv[kt][r] = sf[r];
    }
    __builtin_amdgcn_s_setprio(0);
    if (masked) {
      #pragma unroll
      for (int kt = 0; kt < 8; ++kt) {
        #pragma unroll
        for (int r = 0; r < 4; ++r) {
          int tk = pos0 + kt * 16 + lg * 4 + r - base;
          bool valid = (vtok[tk] != 0) && (tk <= tq);
          sv[kt][r] = valid ? sv[kt][r] * 0.125f : -1e30f;
        }
      }
    } else {
      #pragma unroll
      for (int kt = 0; kt < 8; ++kt)
        #pragma unroll
        for (int r = 0; r < 4; ++r) sv[kt][r] *= 0.125f;
    }
    float pmax = sv[0][0];
    #pragma unroll
    for (int kt = 0; kt < 8; ++kt)
      #pragma unroll
      for (int r = 0; r < 4; ++r) pmax = fmaxf(pmax, sv[kt][r]);
    pmax = fmaxf(pmax, __shfl_xor(pmax, 16));
    pmax = fmaxf(pmax, __shfl_xor(pmax, 32));
    float mnew = fmaxf(m_, pmax);
    float al = __expf(m_ - mnew);
    m_ = mnew;
    float psum = 0.f;
    #pragma unroll
    for (int kt = 0; kt < 8; ++kt)
      #pragma unroll
      for (int r = 0; r < 4; ++r) {
        float pe = __expf(sv[kt][r] - mnew);
        sv[kt][r] = pe;
        psum += pe;
      }
    psum += __shfl_xor(psum, 16);
    psum += __shfl_xor(psum, 32);
    lsum = lsum * al + psum;
    #pragma unroll
    for (int dt = 0; dt < 4; ++dt) {
      f32x4 o = od[dt];
      o[0] *= al; o[1] *= al; o[2] *= al; o[3] *= al;
      od[dt] = o;
    }
    #pragma unroll
    for (int kt = 0; kt < 8; ++kt) {
      uint2 wp;
      asm("v_cvt_pk_bf16_f32 %0, %1, %2" : "=v"(wp.x) : "v"(sv[kt][0]), "v"(sv[kt][1]));
      asm("v_cvt_pk_bf16_f32 %0, %1, %2" : "=v"(wp.y) : "v"(sv[kt][2]), "v"(sv[kt][3]));
      *reinterpret_cast<uint2*>(&pw[PIDX2(lr, kt * 8 + lg * 2)]) = wp;
    }
    bf16x8 pf0 = *reinterpret_cast<const bf16x8*>(&pw[PIDX2(lr, 0 * 16 + lg * 4)]);
    bf16x8 pf1 = *reinterpret_cast<const bf16x8*>(&pw[PIDX2(lr, 1 * 16 + lg * 4)]);
    bf16x8 pf2 = *reinterpret_cast<const bf16x8*>(&pw[PIDX2(lr, 2 * 16 + lg * 4)]);
    bf16x8 pf3 = *reinterpret_cast<const bf16x8*>(&pw[PIDX2(lr, 3 * 16 + lg * 4)]);
    __builtin_amdgcn_s_setprio(1);
    #pragma unroll
    for (int dt = 0; dt < 4; ++dt) {
      int d = dt * 16 + lr;
      #pragma unroll
      for (int m = 0; m < 4; ++m) {
        short4 lo = *reinterpret_cast<const short4*>(&vst[buf][VIDX(d, m * 32 + lg * 8)]);
        short4 hi = *reinterpret_cast<const short4*>(&vst[buf][VIDX(d, m * 32 + lg * 8 + 4)]);
        bf16x8 va = {lo.x, lo.y, lo.z, lo.w, hi.x, hi.y, hi.z, hi.w};
        bf16x8 pf = (m == 0) ? pf0 : (m == 1) ? pf1 : (m == 2) ? pf2 : pf3;
        od[dt] = __builtin_amdgcn_mfma_f32_16x16x32_bf16(va, pf, od[dt], 0, 0, 0);
      }
    }
    __builtin_amdgcn_s_setprio(0);
  };

  {
    int pos0, base; bool masked, part;
    tile_pos(0, pos0, base, masked, part);
    load_regs(pos0);
  }
  for (int i = 0; i < nt; ++i) {
    write_lds(i & 1);
    __syncthreads();
    int pos0, base; bool masked, part;
    tile_pos(i, pos0, base, masked, part);
    if (i + 1 < nt) {
      int npos, nb; bool nm, np;
      tile_pos(i + 1, npos, nb, nm, np);
      load_regs(npos);
    }
    if (part) compute(i & 1, pos0, base, masked);
  }

  float inv = 1.0f / lsum;
  #pragma unroll
  for (int dt = 0; dt < 4; ++dt) {
    ushort4 o4;
    o4.x = (u16)f2bf(od[dt][0] * inv);
    o4.y = (u16)f2bf(od[dt][1] * inv);
    o4.z = (u16)f2bf(od[dt][2] * inv);
    o4.w = (u16)f2bf(od[dt][3] * inv);
    *reinterpret_cast<ushort4*>(
        &ob[((size_t)(b * T_) + tq) * D_ + h * 64 + dt * 16 + lg * 4]) = o4;
  }
}

extern "C" void kernel_launch(void* const* d_in, const int* in_sizes, int n_in,
                              void* d_out, int out_size, void* d_ws, size_t ws_size,
                              hipStream_t stream) {
  (void)in_sizes; (void)n_in; (void)out_size;
  const int* tokens = (const int*)d_in[0];
  const int* mem_ids = (const int*)d_in[1];
  const float* mem_emb = (const float*)d_in[2];
  const float* ssum = (const float*)d_in[3];
  const float* embed = (const float*)d_in[4];
  const float* engram_t = (const float*)d_in[5];
  const float* engram_g = (const float*)d_in[6];
  const float* engram_s = (const float*)d_in[7];
  const float* mem_W = (const float*)d_in[8];
  const float* mem_b = (const float*)d_in[9];
  const float* mem_s = (const float*)d_in[10];
  const float* alpha_g = (const float*)d_in[11];
  const float* ssum_W = (const float*)d_in[12];
  const float* ln1 = (const float*)d_in[13];
  const float* qW = (const float*)d_in[14];
  const float* qbias = (const float*)d_in[15];
  const float* kW = (const float*)d_in[16];
  const float* kbias = (const float*)d_in[17];
  const float* vW = (const float*)d_in[18];
  const float* vbias = (const float*)d_in[19];
  const float* oW = (const float*)d_in[20];
  const float* obias = (const float*)d_in[21];
  const float* ln2 = (const float*)d_in[22];
  const float* w_in = (const float*)d_in[23];
  const float* w_out = (const float*)d_in[24];
  const float* final_s = (const float*)d_in[25];

  const size_t KVSZ = (size_t)B_ * TK_ * D_;
  size_t need = (KVSZ * 2 * 2 * L_) + 120u * 1024 * 1024;
  bool batched = ws_size >= need;

  char* p = (char*)d_ws;
  auto alloc = [&](size_t bytes) { char* r = p; p += (bytes + 255) & ~(size_t)255; return r; };
  u16* kv_b   = (u16*)alloc(KVSZ * 2);
  float* cx   = (float*)alloc((size_t)B_ * T_ * D_ * 4);
  u16* nx_b   = (u16*)alloc((size_t)B_ * T_ * D_ * 2);   // also ob (attn out)
  u16* qb_b   = (u16*)alloc((size_t)B_ * T_ * D_ * 2);   // also mem_tmp f32
  int nkv = batched ? L_ : 1;
  u16* kb_all = (u16*)alloc(KVSZ * 2 * nkv);
  u16* vb_all = (u16*)alloc(KVSZ * 2 * nkv);
  u16* hb;
  if (batched) hb = (u16*)alloc((size_t)B_ * T_ * 2048 * 2);
  else hb = kb_all;  // spans kb+vb
  u16* wqkvoT = (u16*)alloc((size_t)L_ * 4 * D_ * D_ * 2);
  u16* wiT    = (u16*)alloc((size_t)L_ * 4096 * 512 * 2);
  u16* woutT  = (u16*)alloc((size_t)L_ * 512 * 2048 * 2);
  float* ssp  = (float*)alloc((size_t)B_ * D_ * 4);
  float* rc   = (float*)alloc((size_t)TK_ * 32 * 4);
  float* rs   = (float*)alloc((size_t)TK_ * 32 * 4);
  float* mem_tmp = (float*)qb_b;
  u16* ob_b = nx_b;

  // preamble + batched weight conversion
  rope_table_k<<<TK_ * 32 / 64, 64, 0, stream>>>(rc, rs);
  wconv_qkvo_k<<<dim3(8, 8, L_ * 4), 256, 0, stream>>>(qW, kW, vW, oW, wqkvoT);
  wconv_win_k<<<dim3(64, 8, L_), 256, 0, stream>>>(w_in, wiT);
  wconv_wout_k<<<dim3(8, 32, L_), 256, 0, stream>>>(w_out, woutT);
  ssum_proj_k<<<dim3(2, B_), 256, 0, stream>>>(ssum, ssum_W, ssp);
  sgemm_k<<<dim3(8, 8), 256, 0, stream>>>(mem_emb, mem_W, mem_b, mem_tmp, B_ * O_, D_, D_);
  memnorm_k<<<dim3(O_, B_), 128, 0, stream>>>(mem_tmp, mem_s, kv_b);
  engram_k<<<dim3(T_, B_), 128, 0, stream>>>(tokens, mem_ids, engram_t, engram_g, engram_s, kv_b);
  embed_k<<<dim3(T_, B_), 128, 0, stream>>>(tokens, embed, ssp, alpha_g, cx, kv_b);

  if (batched) {
    // all 6 layers' K/V in one XCD-pinned dispatch
    kv_gemm_k<<<dim3(8 * 8 * 9 * L_), 256, 0, stream>>>(kv_b, wqkvoT, kbias, vbias,
                                                        kb_all, vb_all, rc, rs, 0, KVSZ);
  }

  const size_t WSZ = (size_t)D_ * D_;
  for (int l = 0; l < L_; ++l) {
    const u16* wqT = wqkvoT + ((size_t)l * 4 + 0) * WSZ;
    const u16* woT = wqkvoT + ((size_t)l * 4 + 3) * WSZ;
    const u16* wil = wiT + (size_t)l * 4096 * 512;
    const u16* wol = woutT + (size_t)l * 512 * 2048;
    u16* kb_l = batched ? kb_all + (size_t)l * KVSZ : kb_all;
    u16* vb_l = batched ? vb_all + (size_t)l * KVSZ : vb_all;

    rmsnorm_k<1><<<B_ * T_, 128, 0, stream>>>(cx, ln1 + l * D_, nx_b);
    gemm_sm_k<1><<<dim3(8, 64), 256, 0, stream>>>(nx_b, wqT, qbias + l * D_, qb_b,
                                                  B_ * T_, D_, D_, T_, rc, rs);
    if (!batched) {
      kv_gemm_k<<<dim3(8 * 8 * 9), 256, 0, stream>>>(kv_b, wqkvoT, kbias, vbias,
                                                     kb_l, vb_l, rc, rs, l, 0);
    }
    attn_mfma_k<<<dim3(256), 512, 0, stream>>>(qb_b, kb_l, vb_l, tokens, ob_b);
    gemm_sm_k<2><<<dim3(8, 64), 256, 0, stream>>>(ob_b, woT, obias + l * D_, cx,
                                                  B_ * T_, D_, D_, 0, nullptr, nullptr);
    rmsnorm_k<1><<<B_ * T_, 128, 0, stream>>>(cx, ln2 + l * D_, nx_b);
    mlp_in_mfma_k<<<dim3(32, 32), 256, 0, stream>>>(nx_b, wil, hb);
    gemm_sm_k<2><<<dim3(8, 64), 256, 0, stream>>>(hb, wol, nullptr, cx,
                                                  B_ * T_, D_, 2048, 0, nullptr, nullptr);
  }
  rmsnorm_k<0><<<B_ * T_, 128, 0, stream>>>(cx, final_s, d_out);
}

// Round 16
// 1050.367 us; speedup vs baseline: 1.0144x; 1.0144x over previous
//
#include <hip/hip_runtime.h>
#include <hip/hip_bf16.h>
#include <math.h>

#define B_ 4
#define T_ 1024
#define O_ 128
#define D_ 512
#define H_ 8
#define L_ 6
#define TK_ 2176
#define MM_ 100000
#define EH_ 4
#define EHD_ 128
#define HD_ 64

typedef float f32x4 __attribute__((ext_vector_type(4)));
typedef short bf16x8 __attribute__((ext_vector_type(8)));
typedef unsigned short u16;

// PRIMES per reference: base=131, x=base+h*1009; row[i]=x; x=x*31+1 (uint32 wrap)
__device__ __constant__ unsigned int PRIMES_[4][4] = {
  {131u,  4062u,  125923u, 3903614u},
  {1140u, 35341u, 1095572u, 33962733u},
  {2149u, 66620u, 2065221u, 64021852u},
  {3158u, 97899u, 3034870u, 94080971u},
};

__device__ __forceinline__ float wave_sum_f(float v) {
  #pragma unroll
  for (int off = 32; off; off >>= 1) v += __shfl_xor(v, off);
  return v;
}

__device__ __forceinline__ short f2bf(float f) {
  unsigned int u = __float_as_uint(f);
  unsigned int r = (u + 0x7fffu + ((u >> 16) & 1u)) >> 16;
  return (short)r;
}

__device__ __forceinline__ void gload16(const void* g, void* l) {
  __builtin_amdgcn_global_load_lds((const __attribute__((address_space(1))) void*)g,
                                   (__attribute__((address_space(3))) void*)l, 16, 0, 0);
}

// repack within a 16-lane group: input p = bf16(col lr) | bf16(col lr+16)<<16
// output = bf16(col 2*lr) | bf16(col 2*lr+1)<<16  -> 16-lane group covers 64
// contiguous bytes of one row (64 B sector-aligned store).
__device__ __forceinline__ unsigned int repack32(unsigned int p, int lane) {
  int lr = lane & 15;
  int gb = lane & 48;
  unsigned int s0 = __shfl(p, gb + ((2 * lr) & 15), 64);
  unsigned int s1 = __shfl(p, gb + ((2 * lr + 1) & 15), 64);
  return (lr < 8) ? ((s0 & 0xffffu) | (s1 << 16))
                  : ((s0 >> 16) | (s1 & 0xffff0000u));
}

// ---------------- rope tables: cos/sin [TK][32] ----------------
__global__ __launch_bounds__(64) void rope_table_k(float* __restrict__ rc,
                                                   float* __restrict__ rs) {
  int i = blockIdx.x * 64 + threadIdx.x;
  int t = i >> 5, j = i & 31;
  float freq = __powf(10000.0f, -(float)j / 32.0f);
  float ang = (float)t * freq;
  rc[i] = cosf(ang);
  rs[i] = sinf(ang);
}

// ---------------- ssum @ ssum_W -> ssp[B][D] ----------------
__global__ __launch_bounds__(256) void ssum_proj_k(const float* __restrict__ ssum,
                                                   const float* __restrict__ sW,
                                                   float* __restrict__ ssp) {
  int col = blockIdx.x * 256 + threadIdx.x;
  int b = blockIdx.y;
  float acc = 0.f;
  for (int d = 0; d < D_; ++d) acc += ssum[b * D_ + d] * sW[(size_t)d * D_ + col];
  ssp[b * D_ + col] = acc;
}

// ---------------- f32 tiled GEMM (preamble mem projection only) ----------------
__global__ __launch_bounds__(256) void sgemm_k(const float* __restrict__ A,
                                               const float* __restrict__ W,
                                               const float* __restrict__ bias,
                                               float* __restrict__ C,
                                               int M, int N, int K) {
  __shared__ float As[16][68];
  __shared__ float Bs[16][68];
  int tid = threadIdx.x;
  int row0 = blockIdx.y * 64;
  int col0 = blockIdx.x * 64;
  int tx = tid & 15, ty = tid >> 4;
  int am = tid >> 2, ak = (tid & 3) * 4;
  int bk = tid >> 4, bc = (tid & 15) * 4;
  float acc[4][4] = {};
  for (int k0 = 0; k0 < K; k0 += 16) {
    float4 av = *reinterpret_cast<const float4*>(&A[(size_t)(row0 + am) * K + k0 + ak]);
    As[ak + 0][am] = av.x; As[ak + 1][am] = av.y; As[ak + 2][am] = av.z; As[ak + 3][am] = av.w;
    float4 bv = *reinterpret_cast<const float4*>(&W[(size_t)(k0 + bk) * N + col0 + bc]);
    *reinterpret_cast<float4*>(&Bs[bk][bc]) = bv;
    __syncthreads();
    #pragma unroll
    for (int kk = 0; kk < 16; ++kk) {
      float4 a4 = *reinterpret_cast<const float4*>(&As[kk][ty * 4]);
      float4 b4 = *reinterpret_cast<const float4*>(&Bs[kk][tx * 4]);
      float a[4] = {a4.x, a4.y, a4.z, a4.w};
      float b[4] = {b4.x, b4.y, b4.z, b4.w};
      #pragma unroll
      for (int i = 0; i < 4; ++i)
        #pragma unroll
        for (int j = 0; j < 4; ++j) acc[i][j] += a[i] * b[j];
    }
    __syncthreads();
  }
  int cbase = col0 + tx * 4;
  float4 b4 = *reinterpret_cast<const float4*>(&bias[cbase]);
  float bb[4] = {b4.x, b4.y, b4.z, b4.w};
  #pragma unroll
  for (int i = 0; i < 4; ++i) {
    int row = row0 + ty * 4 + i;
    *reinterpret_cast<float4*>(&C[(size_t)row * N + cbase]) =
        make_float4(acc[i][0] + bb[0], acc[i][1] + bb[1], acc[i][2] + bb[2], acc[i][3] + bb[3]);
  }
}

// ---------------- batched weight convert+transpose: f32 [K][N] -> bf16 [N][K] ----------------
__device__ __forceinline__ void wconv_tile(const float* __restrict__ W, u16* __restrict__ wT,
                                           int K, int N) {
  __shared__ float s[64][65];
  int n0 = blockIdx.x * 64, k0 = blockIdx.y * 64;
  int tid = threadIdx.x;
  int kr = tid >> 4, nc = (tid & 15) * 4;
  #pragma unroll
  for (int kk = 0; kk < 4; ++kk) {
    float4 f = *reinterpret_cast<const float4*>(&W[(size_t)(k0 + kr + kk * 16) * N + n0 + nc]);
    s[kr + kk * 16][nc + 0] = f.x; s[kr + kk * 16][nc + 1] = f.y;
    s[kr + kk * 16][nc + 2] = f.z; s[kr + kk * 16][nc + 3] = f.w;
  }
  __syncthreads();
  int nr = tid >> 4, kc = (tid & 15) * 4;
  #pragma unroll
  for (int nn = 0; nn < 4; ++nn) {
    int n = nr + nn * 16;
    ushort4 o;
    o.x = (u16)f2bf(s[kc + 0][n]); o.y = (u16)f2bf(s[kc + 1][n]);
    o.z = (u16)f2bf(s[kc + 2][n]); o.w = (u16)f2bf(s[kc + 3][n]);
    *reinterpret_cast<ushort4*>(&wT[(size_t)(n0 + n) * K + k0 + kc]) = o;
  }
}

__global__ __launch_bounds__(256) void wconv_qkvo_k(const float* __restrict__ qW,
                                                    const float* __restrict__ kW,
                                                    const float* __restrict__ vW,
                                                    const float* __restrict__ oW,
                                                    u16* __restrict__ dst) {
  int z = blockIdx.z;
  int l = z >> 2, which = z & 3;
  const float* src = which == 0 ? qW : which == 1 ? kW : which == 2 ? vW : oW;
  wconv_tile(src + (size_t)l * D_ * D_, dst + (size_t)z * D_ * D_, D_, D_);
}

__global__ __launch_bounds__(256) void wconv_win_k(const float* __restrict__ w_in,
                                                   u16* __restrict__ dst) {
  int l = blockIdx.z;
  wconv_tile(w_in + (size_t)l * 512 * 4096, dst + (size_t)l * 4096 * 512, 512, 4096);
}

__global__ __launch_bounds__(256) void wconv_wout_k(const float* __restrict__ w_out,
                                                    u16* __restrict__ dst) {
  int l = blockIdx.z;
  wconv_tile(w_out + (size_t)l * 2048 * 512, dst + (size_t)l * 512 * 2048, 2048, 512);
}

// ---------------- small MFMA GEMM: 64x64 tile, 4 waves (wave 32x32) ----------------
template<int EPI>
__global__ __launch_bounds__(256) void gemm_sm_k(const u16* __restrict__ A,
                                                 const u16* __restrict__ Bt,
                                                 const float* __restrict__ bias,
                                                 void* __restrict__ Cout,
                                                 int M, int N, int K, int posmod,
                                                 const float* __restrict__ rc,
                                                 const float* __restrict__ rs) {
  __shared__ __align__(16) u16 As[2][64 * 32];
  __shared__ __align__(16) u16 Bs[2][64 * 32];
  int tid = threadIdx.x;
  int w = tid >> 6, lane = tid & 63;
  int lr = lane & 15, lg = lane >> 4;
  int row0 = blockIdx.y * 64, col0 = blockIdx.x * 64;
  int wr = w >> 1, wc = w & 1;
  f32x4 acc[2][2] = {};

  int srow = tid >> 2;
  int skel = (tid & 3) * 8;

  auto stage = [&](int buf, int k0) {
    gload16(A + (size_t)(row0 + srow) * K + k0 + skel, &As[buf][srow * 32 + skel]);
    gload16(Bt + (size_t)(col0 + srow) * K + k0 + skel, &Bs[buf][srow * 32 + skel]);
  };

  stage(0, 0);
  __syncthreads();
  int nk = K >> 5;
  int buf = 0;
  for (int t = 0; t < nk; ++t) {
    if (t + 1 < nk) stage(buf ^ 1, (t + 1) * 32);
    bf16x8 af[2], bf[2];
    #pragma unroll
    for (int i = 0; i < 2; ++i)
      af[i] = *reinterpret_cast<const bf16x8*>(&As[buf][(wr * 32 + i * 16 + lr) * 32 + lg * 8]);
    #pragma unroll
    for (int j = 0; j < 2; ++j)
      bf[j] = *reinterpret_cast<const bf16x8*>(&Bs[buf][(wc * 32 + j * 16 + lr) * 32 + lg * 8]);
    #pragma unroll
    for (int i = 0; i < 2; ++i)
      #pragma unroll
      for (int j = 0; j < 2; ++j)
        acc[i][j] = __builtin_amdgcn_mfma_f32_16x16x32_bf16(af[i], bf[j], acc[i][j], 0, 0, 0);
    __syncthreads();
    buf ^= 1;
  }

  #pragma unroll
  for (int j = 0; j < 2; ++j) {
    int col = col0 + wc * 32 + j * 16 + lr;
    float bs = bias ? bias[col] : 0.f;
    #pragma unroll
    for (int i = 0; i < 2; ++i) {
      #pragma unroll
      for (int r = 0; r < 4; ++r) {
        int row = row0 + wr * 32 + i * 16 + lg * 4 + r;
        float v = acc[i][j][r] + bs;
        if (EPI == 1) {
          int pos = row % posmod;
          int d = col & 63;
          float c = rc[(size_t)pos * 32 + (d >> 1)];
          float s = rs[(size_t)pos * 32 + (d >> 1)];
          float partner = __shfl_xor(v, 1);
          v = (d & 1) ? (partner * s + v * c) : (v * c - partner * s);
        }
        if (EPI == 2) {
          float* Cf = (float*)Cout;
          Cf[(size_t)row * N + col] += v;
        } else {
          u16* Cb = (u16*)Cout;
          Cb[(size_t)row * N + col] = (u16)f2bf(v);
        }
      }
    }
  }
}

// ---------------- fused K+V projection, XCD-pinned grid, repacked 64B stores ----------------
__global__ __launch_bounds__(256) void kv_gemm_k(const u16* __restrict__ A,
                                                 const u16* __restrict__ wqkvoT,
                                                 const float* __restrict__ kbias_all,
                                                 const float* __restrict__ vbias_all,
                                                 u16* __restrict__ kb_base,
                                                 u16* __restrict__ vb_base,
                                                 const float* __restrict__ rc,
                                                 const float* __restrict__ rs,
                                                 int l0, size_t ostride) {
  __shared__ __align__(16) u16 As[2][128 * 32];
  __shared__ __align__(16) u16 Bk[2][64 * 32];
  __shared__ __align__(16) u16 Bv[2][64 * 32];
  const int K = 512, N = 512;
  int bid = blockIdx.x;
  int c_ = bid & 7;
  int x_ = (bid >> 3) & 7;
  int rest = bid >> 6;
  int yh = rest % 9;
  int z = rest / 9;
  int y_ = yh * 8 + c_;
  if (y_ >= 68) return;
  int l = l0 + z;
  const u16* wkT = wqkvoT + ((size_t)l * 4 + 1) * (D_ * D_);
  const u16* wvT = wqkvoT + ((size_t)l * 4 + 2) * (D_ * D_);
  const float* kbias = kbias_all + l * D_;
  const float* vbias = vbias_all + l * D_;
  u16* kb = kb_base + (size_t)z * ostride;
  u16* vb = vb_base + (size_t)z * ostride;
  int tid = threadIdx.x;
  int w = tid >> 6, lane = tid & 63;
  int lr = lane & 15, lg = lane >> 4;
  int row0 = y_ * 128, col0 = x_ * 64;
  int wr = w >> 1, wc = w & 1;
  f32x4 ak_[4][2] = {};
  f32x4 av_[4][2] = {};

  int srow = lane >> 2;
  int skel = (lane & 3) * 8;

  auto stage = [&](int buf, int k0) {
    #pragma unroll
    for (int ci = 0; ci < 2; ++ci) {
      int c = w * 2 + ci;
      gload16(A + (size_t)(row0 + c * 16 + srow) * K + k0 + skel, &As[buf][c * 512]);
    }
    gload16(wkT + (size_t)(col0 + w * 16 + srow) * K + k0 + skel, &Bk[buf][w * 512]);
    gload16(wvT + (size_t)(col0 + w * 16 + srow) * K + k0 + skel, &Bv[buf][w * 512]);
  };

  stage(0, 0);
  __syncthreads();
  int buf = 0;
  for (int t = 0; t < 16; ++t) {
    if (t + 1 < 16) stage(buf ^ 1, (t + 1) * 32);
    bf16x8 af[4], bk[2], bv[2];
    #pragma unroll
    for (int i = 0; i < 4; ++i)
      af[i] = *reinterpret_cast<const bf16x8*>(&As[buf][(wr * 64 + i * 16 + lr) * 32 + lg * 8]);
    #pragma unroll
    for (int j = 0; j < 2; ++j) {
      bk[j] = *reinterpret_cast<const bf16x8*>(&Bk[buf][(wc * 32 + j * 16 + lr) * 32 + lg * 8]);
      bv[j] = *reinterpret_cast<const bf16x8*>(&Bv[buf][(wc * 32 + j * 16 + lr) * 32 + lg * 8]);
    }
    #pragma unroll
    for (int i = 0; i < 4; ++i)
      #pragma unroll
      for (int j = 0; j < 2; ++j) {
        ak_[i][j] = __builtin_amdgcn_mfma_f32_16x16x32_bf16(af[i], bk[j], ak_[i][j], 0, 0, 0);
        av_[i][j] = __builtin_amdgcn_mfma_f32_16x16x32_bf16(af[i], bv[j], av_[i][j], 0, 0, 0);
      }
    __syncthreads();
    buf ^= 1;
  }

  // epilogue: per (i,r) compute both j values, rope+bias, pack -> repack -> u32 store
  int c0 = col0 + wc * 32 + lr;
  int c1 = c0 + 16;
  float kbs0 = kbias[c0], kbs1 = kbias[c1];
  float vbs0 = vbias[c0], vbs1 = vbias[c1];
  int d0 = c0 & 63, d1 = c1 & 63;
  size_t colbase = col0 + wc * 32 + 2 * lr;
  #pragma unroll
  for (int i = 0; i < 4; ++i) {
    #pragma unroll
    for (int r = 0; r < 4; ++r) {
      int row = row0 + wr * 64 + i * 16 + lg * 4 + r;
      int pos = row % TK_;
      float k0v = ak_[i][0][r] + kbs0;
      {
        float c = rc[(size_t)pos * 32 + (d0 >> 1)];
        float s = rs[(size_t)pos * 32 + (d0 >> 1)];
        float partner = __shfl_xor(k0v, 1);
        k0v = (d0 & 1) ? (partner * s + k0v * c) : (k0v * c - partner * s);
      }
      float k1v = ak_[i][1][r] + kbs1;
      {
        float c = rc[(size_t)pos * 32 + (d1 >> 1)];
        float s = rs[(size_t)pos * 32 + (d1 >> 1)];
        float partner = __shfl_xor(k1v, 1);
        k1v = (d1 & 1) ? (partner * s + k1v * c) : (k1v * c - partner * s);
      }
      unsigned int pk = (unsigned int)(u16)f2bf(k0v) | ((unsigned int)(u16)f2bf(k1v) << 16);
      *reinterpret_cast<unsigned int*>(&kb[(size_t)row * N + colbase]) = repack32(pk, lane);
      float v0v = av_[i][0][r] + vbs0;
      float v1v = av_[i][1][r] + vbs1;
      unsigned int pv = (unsigned int)(u16)f2bf(v0v) | ((unsigned int)(u16)f2bf(v1v) << 16);
      *reinterpret_cast<unsigned int*>(&vb[(size_t)row * N + colbase]) = repack32(pv, lane);
    }
  }
}

// ---------------- fused MLP-in MFMA (64-col dual tile, direct stores) ----------------
__global__ __launch_bounds__(256) void mlp_in_mfma_k(const u16* __restrict__ A,
                                                     const u16* __restrict__ wiT,
                                                     u16* __restrict__ Hout) {
  __shared__ __align__(16) u16 As[2][128 * 32];
  __shared__ __align__(16) u16 Bg[2][64 * 32];
  __shared__ __align__(16) u16 Bv[2][64 * 32];
  int tid = threadIdx.x;
  int w = tid >> 6, lane = tid & 63;
  int lr = lane & 15, lg = lane >> 4;
  int hc0 = blockIdx.x * 64, row0 = blockIdx.y * 128;
  int wr = w >> 1, wc = w & 1;
  f32x4 ag[4][2] = {};
  f32x4 av[4][2] = {};
  const int K = 512;

  int srow = lane >> 2;
  int skel = (lane & 3) * 8;

  auto stage = [&](int buf, int k0) {
    #pragma unroll
    for (int ci = 0; ci < 2; ++ci) {
      int c = w * 2 + ci;
      gload16(A + (size_t)(row0 + c * 16 + srow) * K + k0 + skel, &As[buf][c * 512]);
    }
    gload16(wiT + (size_t)(hc0 + w * 16 + srow) * K + k0 + skel, &Bg[buf][w * 512]);
    gload16(wiT + (size_t)(2048 + hc0 + w * 16 + srow) * K + k0 + skel, &Bv[buf][w * 512]);
  };

  stage(0, 0);
  __syncthreads();
  int buf = 0;
  for (int t = 0; t < 16; ++t) {
    if (t + 1 < 16) stage(buf ^ 1, (t + 1) * 32);
    bf16x8 af[4], bg[2], bv[2];
    #pragma unroll
    for (int i = 0; i < 4; ++i)
      af[i] = *reinterpret_cast<const bf16x8*>(&As[buf][(wr * 64 + i * 16 + lr) * 32 + lg * 8]);
    #pragma unroll
    for (int j = 0; j < 2; ++j) {
      bg[j] = *reinterpret_cast<const bf16x8*>(&Bg[buf][(wc * 32 + j * 16 + lr) * 32 + lg * 8]);
      bv[j] = *reinterpret_cast<const bf16x8*>(&Bv[buf][(wc * 32 + j * 16 + lr) * 32 + lg * 8]);
    }
    #pragma unroll
    for (int i = 0; i < 4; ++i)
      #pragma unroll
      for (int j = 0; j < 2; ++j) {
        ag[i][j] = __builtin_amdgcn_mfma_f32_16x16x32_bf16(af[i], bg[j], ag[i][j], 0, 0, 0);
        av[i][j] = __builtin_amdgcn_mfma_f32_16x16x32_bf16(af[i], bv[j], av[i][j], 0, 0, 0);
      }
    __syncthreads();
    buf ^= 1;
  }

  #pragma unroll
  for (int j = 0; j < 2; ++j) {
    int col = hc0 + wc * 32 + j * 16 + lr;
    #pragma unroll
    for (int i = 0; i < 4; ++i) {
      #pragma unroll
      for (int r = 0; r < 4; ++r) {
        int row = row0 + wr * 64 + i * 16 + lg * 4 + r;
        float g = ag[i][j][r];
        float sg = g / (1.f + __expf(-g));
        Hout[(size_t)row * 2048 + col] = (u16)f2bf(sg * av[i][j][r]);
      }
    }
  }
}

// ---------------- rmsnorm rows ----------------
template<int OUTBF>
__global__ __launch_bounds__(128) void rmsnorm_k(const float* __restrict__ in,
                                                 const float* __restrict__ scale,
                                                 void* __restrict__ out) {
  int row = blockIdx.x;
  int tid = threadIdx.x;
  float4 v = *reinterpret_cast<const float4*>(&in[(size_t)row * D_ + tid * 4]);
  float ss = v.x * v.x + v.y * v.y + v.z * v.z + v.w * v.w;
  ss = wave_sum_f(ss);
  __shared__ float red[2];
  if ((tid & 63) == 0) red[tid >> 6] = ss;
  __syncthreads();
  ss = red[0] + red[1];
  float inv = 1.0f / sqrtf(ss / (float)D_ + 1e-6f);
  float4 sc = *reinterpret_cast<const float4*>(&scale[tid * 4]);
  float o0 = v.x * inv * sc.x, o1 = v.y * inv * sc.y, o2 = v.z * inv * sc.z, o3 = v.w * inv * sc.w;
  if (OUTBF) {
    ushort4 o;
    o.x = (u16)f2bf(o0); o.y = (u16)f2bf(o1); o.z = (u16)f2bf(o2); o.w = (u16)f2bf(o3);
    *reinterpret_cast<ushort4*>((u16*)out + (size_t)row * D_ + tid * 4) = o;
  } else {
    *reinterpret_cast<float4*>((float*)out + (size_t)row * D_ + tid * 4) =
        make_float4(o0, o1, o2, o3);
  }
}

// ---------------- mem rows ----------------
__global__ __launch_bounds__(128) void memnorm_k(const float* __restrict__ tmp,
                                                 const float* __restrict__ scale,
                                                 u16* __restrict__ kv) {
  int o = blockIdx.x, b = blockIdx.y;
  int tid = threadIdx.x;
  float4 v = *reinterpret_cast<const float4*>(&tmp[(size_t)(b * O_ + o) * D_ + tid * 4]);
  float ss = v.x * v.x + v.y * v.y + v.z * v.z + v.w * v.w;
  ss = wave_sum_f(ss);
  __shared__ float red[2];
  if ((tid & 63) == 0) red[tid >> 6] = ss;
  __syncthreads();
  ss = red[0] + red[1];
  float inv = 1.0f / sqrtf(ss / (float)D_ + 1e-6f);
  float4 sc = *reinterpret_cast<const float4*>(&scale[tid * 4]);
  ushort4 oo;
  oo.x = (u16)f2bf(v.x * inv * sc.x); oo.y = (u16)f2bf(v.y * inv * sc.y);
  oo.z = (u16)f2bf(v.z * inv * sc.z); oo.w = (u16)f2bf(v.w * inv * sc.w);
  *reinterpret_cast<ushort4*>(&kv[(size_t)(b * TK_ + o) * D_ + tid * 4]) = oo;
}

// ---------------- engram rows ----------------
__global__ __launch_bounds__(128) void engram_k(const int* __restrict__ tokens,
                                                const int* __restrict__ mem_ids,
                                                const float* __restrict__ etab,
                                                const float* __restrict__ egate,
                                                const float* __restrict__ escale,
                                                u16* __restrict__ kv) {
  int t = blockIdx.x, b = blockIdx.y;
  int tid = threadIdx.x;
  unsigned int toks[4];
  #pragma unroll
  for (int i = 0; i < 4; ++i) {
    int idx = t - i;
    toks[i] = (idx >= 0) ? (unsigned int)tokens[b * T_ + idx]
                         : (unsigned int)mem_ids[b * O_ + O_ + idx];
  }
  int c = tid * 4;
  int h = c >> 7;
  int e = c & 127;
  unsigned int hs = 0;
  #pragma unroll
  for (int i = 0; i < 4; ++i) hs += toks[i] * PRIMES_[h][i];
  int idxh = (int)(hs % (unsigned int)MM_);
  float4 r = *reinterpret_cast<const float4*>(&etab[((size_t)idxh * EH_ + h) * EHD_ + e]);
  float4 g = *reinterpret_cast<const float4*>(&egate[h * EHD_ + e]);
  float4 val;
  val.x = r.x / (1.f + __expf(-g.x));
  val.y = r.y / (1.f + __expf(-g.y));
  val.z = r.z / (1.f + __expf(-g.z));
  val.w = r.w / (1.f + __expf(-g.w));
  float ss = val.x * val.x + val.y * val.y + val.z * val.z + val.w * val.w;
  ss = wave_sum_f(ss);
  __shared__ float red[2];
  if ((tid & 63) == 0) red[tid >> 6] = ss;
  __syncthreads();
  ss = red[0] + red[1];
  float inv = 1.0f / sqrtf(ss / (float)D_ + 1e-6f);
  float4 sc = *reinterpret_cast<const float4*>(&escale[c]);
  ushort4 oo;
  oo.x = (u16)f2bf(val.x * inv * sc.x); oo.y = (u16)f2bf(val.y * inv * sc.y);
  oo.z = (u16)f2bf(val.z * inv * sc.z); oo.w = (u16)f2bf(val.w * inv * sc.w);
  *reinterpret_cast<ushort4*>(&kv[(size_t)(b * TK_ + O_ + t) * D_ + c]) = oo;
}

// ---------------- embed + ssum inject ----------------
__global__ __launch_bounds__(128) void embed_k(const int* __restrict__ tokens,
                                               const float* __restrict__ etab,
                                               const float* __restrict__ ssp,
                                               const float* __restrict__ alpha_g,
                                               float* __restrict__ cx,
                                               u16* __restrict__ kv) {
  int t = blockIdx.x, b = blockIdx.y;
  int tid = threadIdx.x;
  int c = tid * 4;
  int tok = tokens[b * T_ + t];
  float4 e = *reinterpret_cast<const float4*>(&etab[(size_t)tok * D_ + c]);
  float4 sp = *reinterpret_cast<const float4*>(&ssp[b * D_ + c]);
  float4 ag = *reinterpret_cast<const float4*>(&alpha_g[c]);
  float4 x;
  x.x = e.x + sp.x / (1.f + __expf(-ag.x));
  x.y = e.y + sp.y / (1.f + __expf(-ag.y));
  x.z = e.z + sp.z / (1.f + __expf(-ag.z));
  x.w = e.w + sp.w / (1.f + __expf(-ag.w));
  *reinterpret_cast<float4*>(&cx[(size_t)(b * T_ + t) * D_ + c]) = x;
  ushort4 oo;
  oo.x = (u16)f2bf(x.x); oo.y = (u16)f2bf(x.y);
  oo.z = (u16)f2bf(x.z); oo.w = (u16)f2bf(x.w);
  *reinterpret_cast<ushort4*>(&kv[(size_t)(b * TK_ + O_ + T_ + t) * D_ + c]) = oo;
}

// ---------------- MFMA flash attention v6: KVBLK=128, paired q-tiles ----------------
#define KIDX8(r, c) (((r) << 6) + ((c) ^ (((r) & 7) << 3)))
#define VIDX(d, c)  (((d) << 7) + ((c) ^ (((d) & 15) << 2)))
#define PIDX2(q, o) (((q) << 6) + ((o) ^ (((q) & 15) << 2)))

__global__ __launch_bounds__(512) void attn_mfma_k(const u16* __restrict__ qb,
                                                   const u16* __restrict__ kb,
                                                   const u16* __restrict__ vb,
                                                   const int* __restrict__ tokens,
                                                   u16* __restrict__ ob) {
  __shared__ __align__(16) short ks[2][128 * 64];
  __shared__ __align__(16) short vst[2][64 * 128];        // transposed: [d][k]
  __shared__ __align__(16) unsigned int pbuf[8][16 * 64]; // per-wave P^T packed pairs
  __shared__ unsigned char vtok[T_];

  int fid = blockIdx.x;       // 256 blocks
  int h = fid & 7;
  int s = fid >> 3;           // 0..31
  int pair = s & 7;           // bxA = pair, bxB = 15 - pair
  int b = s >> 3;             // 0..3
  int bxA = pair, bxB = 15 - pair;

  int tid = threadIdx.x;
  int w = tid >> 6, lane = tid & 63;
  int lr = lane & 15;
  int lg = lane >> 4;
  int myBx = (w < 4) ? bxA : bxB;
  int qw0 = myBx * 64 + (w & 3) * 16;
  int tq = qw0 + lr;  // this lane's query row

  for (int i = tid; i < T_; i += 512) vtok[i] = (tokens[b * T_ + i] != 0);

  bf16x8 aq[2];  // Q for this lane's q row: B-operand (col=lr, d=lg*8..)
  {
    const u16* qp = &qb[((size_t)(b * T_) + tq) * D_ + h * 64];
    aq[0] = *reinterpret_cast<const bf16x8*>(qp + lg * 8);
    aq[1] = *reinterpret_cast<const bf16x8*>(qp + 32 + lg * 8);
  }

  float m_ = -1e30f, lsum = 0.f;
  f32x4 od[4];
  #pragma unroll
  for (int dt = 0; dt < 4; ++dt) od[dt] = (f32x4){0.f, 0.f, 0.f, 0.f};

  int sr = tid >> 2;
  int sc = (tid & 3) * 16;
  int k4 = (tid >> 4) * 4;
  int vc = (tid & 15) * 4;

  int te = (bxB >> 1) + 1;
  int myTe = myBx >> 1;
  int nt = 1 + 2 * te;
  auto tile_pos = [&](int i, int& pos0, int& base, bool& masked, bool& part) {
    if (i < 1) { pos0 = 0; base = 0; masked = false; part = true; }
    else if (i < 1 + te) {
      int t = i - 1;
      pos0 = O_ + t * 128; base = O_; masked = true; part = (t <= myTe);
    } else {
      int t = i - 1 - te;
      pos0 = O_ + T_ + t * 128; base = O_ + T_; masked = true; part = (t <= myTe);
    }
  };

  bf16x8 pk0, pk1;
  short4 pv0, pv1, pv2, pv3;

  auto load_regs = [&](int pos0) {
    const u16* kg = &kb[((size_t)(b * TK_) + pos0 + sr) * D_ + h * 64 + sc];
    pk0 = *reinterpret_cast<const bf16x8*>(kg);
    pk1 = *reinterpret_cast<const bf16x8*>(kg + 8);
    const u16* vg = &vb[((size_t)(b * TK_) + pos0 + k4) * D_ + h * 64 + vc];
    pv0 = *reinterpret_cast<const short4*>(vg);
    pv1 = *reinterpret_cast<const short4*>(vg + D_);
    pv2 = *reinterpret_cast<const short4*>(vg + 2 * D_);
    pv3 = *reinterpret_cast<const short4*>(vg + 3 * D_);
  };

  auto write_lds = [&](int buf) {
    *reinterpret_cast<bf16x8*>(&ks[buf][KIDX8(sr, sc)]) = pk0;
    *reinterpret_cast<bf16x8*>(&ks[buf][KIDX8(sr, sc + 8)]) = pk1;
    short4 t0 = make_short4(pv0.x, pv1.x, pv2.x, pv3.x);
    short4 t1 = make_short4(pv0.y, pv1.y, pv2.y, pv3.y);
    short4 t2 = make_short4(pv0.z, pv1.z, pv2.z, pv3.z);
    short4 t3 = make_short4(pv0.w, pv1.w, pv2.w, pv3.w);
    *reinterpret_cast<short4*>(&vst[buf][VIDX(vc + 0, k4)]) = t0;
    *reinterpret_cast<short4*>(&vst[buf][VIDX(vc + 1, k4)]) = t1;
    *reinterpret_cast<short4*>(&vst[buf][VIDX(vc + 2, k4)]) = t2;
    *reinterpret_cast<short4*>(&vst[buf][VIDX(vc + 3, k4)]) = t3;
  };

  unsigned int* pw = (unsigned int*)pbuf[w];

  auto compute = [&](int buf, int pos0, int base, bool masked) {
    float sv[8][4];
    __builtin_amdgcn_s_setprio(1);
    #pragma unroll
    for (int kt = 0; kt < 8; ++kt) {
      bf16x8 ka0 = *reinterpret_cast<const bf16x8*>(&ks[buf][KIDX8(kt * 16 + lr, lg * 8)]);
      bf16x8 ka1 = *reinterpret_cast<const bf16x8*>(&ks[buf][KIDX8(kt * 16 + lr, 32 + lg * 8)]);
      f32x4 sf = (f32x4){0.f, 0.f, 0.f, 0.f};
      sf = __builtin_amdgcn_mfma_f32_16x16x32_bf16(ka0, aq[0], sf, 0, 0, 0);
      sf = __builtin_amdgcn_mfma_f32_16x16x32_bf16(ka1, aq[1], sf, 0, 0, 0);
      #pragma unroll
      for (int r = 0; r < 4; ++r) sv[kt][r] = sf[r];
    }
    __builtin_amdgcn_s_setprio(0);
    if (masked) {
      #pragma unroll
      for (int kt = 0; kt < 8; ++kt) {
        #pragma unroll
        for (int r = 0; r < 4; ++r) {
          int tk = pos0 + kt * 16 + lg * 4 + r - base;
          bool valid = (vtok[tk] != 0) && (tk <= tq);
          sv[kt][r] = valid ? sv[kt][r] * 0.125f : -1e30f;
        }
      }
    } else {
      #pragma unroll
      for (int kt = 0; kt < 8; ++kt)
        #pragma unroll
        for (int r = 0; r < 4; ++r) sv[kt][r] *= 0.125f;
    }
    float pmax = sv[0][0];
    #pragma unroll
    for (int kt = 0; kt < 8; ++kt)
      #pragma unroll
      for (int r = 0; r < 4; ++r) pmax = fmaxf(pmax, sv[kt][r]);
    pmax = fmaxf(pmax, __shfl_xor(pmax, 16));
    pmax = fmaxf(pmax, __shfl_xor(pmax, 32));
    float mnew = fmaxf(m_, pmax);
    float al = __expf(m_ - mnew);
    m_ = mnew;
    float psum = 0.f;
    #pragma unroll
    for (int kt = 0; kt < 8; ++kt)
      #pragma unroll
      for (int r = 0; r < 4; ++r) {
        float pe = __expf(sv[kt][r] - mnew);
        sv[kt][r] = pe;
        psum += pe;
      }
    psum += __shfl_xor(psum, 16);
    psum += __shfl_xor(psum, 32);
    lsum = lsum * al + psum;
    #pragma unroll
    for (int dt = 0; dt < 4; ++dt) {
      f32x4 o = od[dt];
      o[0] *= al; o[1] *= al; o[2] *= al; o[3] *= al;
      od[dt] = o;
    }
    #pragma unroll
    for (int kt = 0; kt < 8; ++kt) {
      uint2 wp;
      asm("v_cvt_pk_bf16_f32 %0, %1, %2" : "=v"(wp.x) : "v"(sv[kt][0]), "v"(sv[kt][1]));
      asm("v_cvt_pk_bf16_f32 %0, %1, %2" : "=v"(wp.y) : "v"(sv[kt][2]), "v"(sv[kt][3]));
      *reinterpret_cast<uint2*>(&pw[PIDX2(lr, kt * 8 + lg * 2)]) = wp;
    }
    bf16x8 pf0 = *reinterpret_cast<const bf16x8*>(&pw[PIDX2(lr, 0 * 16 + lg * 4)]);
    bf16x8 pf1 = *reinterpret_cast<const bf16x8*>(&pw[PIDX2(lr, 1 * 16 + lg * 4)]);
    bf16x8 pf2 = *reinterpret_cast<const bf16x8*>(&pw[PIDX2(lr, 2 * 16 + lg * 4)]);
    bf16x8 pf3 = *reinterpret_cast<const bf16x8*>(&pw[PIDX2(lr, 3 * 16 + lg * 4)]);
    __builtin_amdgcn_s_setprio(1);
    #pragma unroll
    for (int dt = 0; dt < 4; ++dt) {
      int d = dt * 16 + lr;
      #pragma unroll
      for (int m = 0; m < 4; ++m) {
        short4 lo = *reinterpret_cast<const short4*>(&vst[buf][VIDX(d, m * 32 + lg * 8)]);
        short4 hi = *reinterpret_cast<const short4*>(&vst[buf][VIDX(d, m * 32 + lg * 8 + 4)]);
        bf16x8 va = {lo.x, lo.y, lo.z, lo.w, hi.x, hi.y, hi.z, hi.w};
        bf16x8 pf = (m == 0) ? pf0 : (m == 1) ? pf1 : (m == 2) ? pf2 : pf3;
        od[dt] = __builtin_amdgcn_mfma_f32_16x16x32_bf16(va, pf, od[dt], 0, 0, 0);
      }
    }
    __builtin_amdgcn_s_setprio(0);
  };

  {
    int pos0, base; bool masked, part;
    tile_pos(0, pos0, base, masked, part);
    load_regs(pos0);
  }
  for (int i = 0; i < nt; ++i) {
    write_lds(i & 1);
    __syncthreads();
    int pos0, base; bool masked, part;
    tile_pos(i, pos0, base, masked, part);
    if (i + 1 < nt) {
      int npos, nb; bool nm, np;
      tile_pos(i + 1, npos, nb, nm, np);
      load_regs(npos);
    }
    if (part) compute(i & 1, pos0, base, masked);
  }

  float inv = 1.0f / lsum;
  #pragma unroll
  for (int dt = 0; dt < 4; ++dt) {
    ushort4 o4;
    o4.x = (u16)f2bf(od[dt][0] * inv);
    o4.y = (u16)f2bf(od[dt][1] * inv);
    o4.z = (u16)f2bf(od[dt][2] * inv);
    o4.w = (u16)f2bf(od[dt][3] * inv);
    *reinterpret_cast<ushort4*>(
        &ob[((size_t)(b * T_) + tq) * D_ + h * 64 + dt * 16 + lg * 4]) = o4;
  }
}

extern "C" void kernel_launch(void* const* d_in, const int* in_sizes, int n_in,
                              void* d_out, int out_size, void* d_ws, size_t ws_size,
                              hipStream_t stream) {
  (void)in_sizes; (void)n_in; (void)out_size;
  const int* tokens = (const int*)d_in[0];
  const int* mem_ids = (const int*)d_in[1];
  const float* mem_emb = (const float*)d_in[2];
  const float* ssum = (const float*)d_in[3];
  const float* embed = (const float*)d_in[4];
  const float* engram_t = (const float*)d_in[5];
  const float* engram_g = (const float*)d_in[6];
  const float* engram_s = (const float*)d_in[7];
  const float* mem_W = (const float*)d_in[8];
  const float* mem_b = (const float*)d_in[9];
  const float* mem_s = (const float*)d_in[10];
  const float* alpha_g = (const float*)d_in[11];
  const float* ssum_W = (const float*)d_in[12];
  const float* ln1 = (const float*)d_in[13];
  const float* qW = (const float*)d_in[14];
  const float* qbias = (const float*)d_in[15];
  const float* kW = (const float*)d_in[16];
  const float* kbias = (const float*)d_in[17];
  const float* vW = (const float*)d_in[18];
  const float* vbias = (const float*)d_in[19];
  const float* oW = (const float*)d_in[20];
  const float* obias = (const float*)d_in[21];
  const float* ln2 = (const float*)d_in[22];
  const float* w_in = (const float*)d_in[23];
  const float* w_out = (const float*)d_in[24];
  const float* final_s = (const float*)d_in[25];

  const size_t KVSZ = (size_t)B_ * TK_ * D_;
  size_t need = (KVSZ * 2 * 2 * L_) + 120u * 1024 * 1024;
  bool batched = ws_size >= need;

  char* p = (char*)d_ws;
  auto alloc = [&](size_t bytes) { char* r = p; p += (bytes + 255) & ~(size_t)255; return r; };
  u16* kv_b   = (u16*)alloc(KVSZ * 2);
  float* cx   = (float*)alloc((size_t)B_ * T_ * D_ * 4);
  u16* nx_b   = (u16*)alloc((size_t)B_ * T_ * D_ * 2);   // also ob (attn out)
  u16* qb_b   = (u16*)alloc((size_t)B_ * T_ * D_ * 2);   // also mem_tmp f32
  int nkv = batched ? L_ : 1;
  u16* kb_all = (u16*)alloc(KVSZ * 2 * nkv);
  u16* vb_all = (u16*)alloc(KVSZ * 2 * nkv);
  u16* hb;
  if (batched) hb = (u16*)alloc((size_t)B_ * T_ * 2048 * 2);
  else hb = kb_all;  // spans kb+vb
  u16* wqkvoT = (u16*)alloc((size_t)L_ * 4 * D_ * D_ * 2);
  u16* wiT    = (u16*)alloc((size_t)L_ * 4096 * 512 * 2);
  u16* woutT  = (u16*)alloc((size_t)L_ * 512 * 2048 * 2);
  float* ssp  = (float*)alloc((size_t)B_ * D_ * 4);
  float* rc   = (float*)alloc((size_t)TK_ * 32 * 4);
  float* rs   = (float*)alloc((size_t)TK_ * 32 * 4);
  float* mem_tmp = (float*)qb_b;
  u16* ob_b = nx_b;

  // preamble + batched weight conversion
  rope_table_k<<<TK_ * 32 / 64, 64, 0, stream>>>(rc, rs);
  wconv_qkvo_k<<<dim3(8, 8, L_ * 4), 256, 0, stream>>>(qW, kW, vW, oW, wqkvoT);
  wconv_win_k<<<dim3(64, 8, L_), 256, 0, stream>>>(w_in, wiT);
  wconv_wout_k<<<dim3(8, 32, L_), 256, 0, stream>>>(w_out, woutT);
  ssum_proj_k<<<dim3(2, B_), 256, 0, stream>>>(ssum, ssum_W, ssp);
  sgemm_k<<<dim3(8, 8), 256, 0, stream>>>(mem_emb, mem_W, mem_b, mem_tmp, B_ * O_, D_, D_);
  memnorm_k<<<dim3(O_, B_), 128, 0, stream>>>(mem_tmp, mem_s, kv_b);
  engram_k<<<dim3(T_, B_), 128, 0, stream>>>(tokens, mem_ids, engram_t, engram_g, engram_s, kv_b);
  embed_k<<<dim3(T_, B_), 128, 0, stream>>>(tokens, embed, ssp, alpha_g, cx, kv_b);

  if (batched) {
    // all 6 layers' K/V in one XCD-pinned dispatch
    kv_gemm_k<<<dim3(8 * 8 * 9 * L_), 256, 0, stream>>>(kv_b, wqkvoT, kbias, vbias,
                                                        kb_all, vb_all, rc, rs, 0, KVSZ);
  }

  const size_t WSZ = (size_t)D_ * D_;
  for (int l = 0; l < L_; ++l) {
    const u16* wqT = wqkvoT + ((size_t)l * 4 + 0) * WSZ;
    const u16* woT = wqkvoT + ((size_t)l * 4 + 3) * WSZ;
    const u16* wil = wiT + (size_t)l * 4096 * 512;
    const u16* wol = woutT + (size_t)l * 512 * 2048;
    u16* kb_l = batched ? kb_all + (size_t)l * KVSZ : kb_all;
    u16* vb_l = batched ? vb_all + (size_t)l * KVSZ : vb_all;

    rmsnorm_k<1><<<B_ * T_, 128, 0, stream>>>(cx, ln1 + l * D_, nx_b);
    gemm_sm_k<1><<<dim3(8, 64), 256, 0, stream>>>(nx_b, wqT, qbias + l * D_, qb_b,
                                                  B_ * T_, D_, D_, T_, rc, rs);
    if (!batched) {
      kv_gemm_k<<<dim3(8 * 8 * 9), 256, 0, stream>>>(kv_b, wqkvoT, kbias, vbias,
                                                     kb_l, vb_l, rc, rs, l, 0);
    }
    attn_mfma_k<<<dim3(256), 512, 0, stream>>>(qb_b, kb_l, vb_l, tokens, ob_b);
    gemm_sm_k<2><<<dim3(8, 64), 256, 0, stream>>>(ob_b, woT, obias + l * D_, cx,
                                                  B_ * T_, D_, D_, 0, nullptr, nullptr);
    rmsnorm_k<1><<<B_ * T_, 128, 0, stream>>>(cx, ln2 + l * D_, nx_b);
    mlp_in_mfma_k<<<dim3(32, 32), 256, 0, stream>>>(nx_b, wil, hb);
    gemm_sm_k<2><<<dim3(8, 64), 256, 0, stream>>>(hb, wol, nullptr, cx,
                                                  B_ * T_, D_, 2048, 0, nullptr, nullptr);
  }
  rmsnorm_k<0><<<B_ * T_, 128, 0, stream>>>(cx, final_s, d_out);
}